// Round 7
// baseline (63.873 us; speedup 1.0000x reference)
//
#include <hip/hip_runtime.h>

#define CCH 128
#define SP  4096          // 64*64 spatial positions per (b,c)
#define BSTR 11           // G-band stride per sh (floats); odd -> bank spread
#define BROWS 10          // band rows rb in [0,10)
#define BSZ (64 * BSTR)   // 704 floats per band
#define GTOT (9 * BSZ)    // 6336 floats; +1 sentinel slot at g[0]
#define T16_OFF 65536     // byte offset of the u16 (s=8) table in d_ws

__device__ __forceinline__ float sigmoidf_(float z) {
  return 1.0f / (1.0f + __expf(-z));
}

// Band-local gather offset for tap s at output wh: 1 + s*BSZ + sh*BSTR + rb,
// or 0 (sentinel -> g[0] = 0.0f) when the source pixel is out of bounds.
__device__ __forceinline__ int tap_off(int s, int wh) {
  int q  = (s << 12) + wh;     // flat index into torch's reinterpreted view
  int wi = q / 576;  int r  = q - wi * 576;
  int hi = r / 9;    int kk = r - hi * 9;
  int di = kk / 3,   dj = kk - di * 3;
  int sw = wi + di - 1, sh = hi + dj - 1;
  bool valid = ((unsigned)sw < 64u) & ((unsigned)sh < 64u);
  int wilo = (s * 64) / 9;     // first source row of band s
  return valid ? (1 + s * BSZ + sh * BSTR + (sw - wilo + 1)) : 0;
}

// One-time table: taps packed as 4 u32 pairs (s=0..7) + 1 u16 (s=8) per wh.
__global__ __launch_bounds__(256) void k_tbl(unsigned* __restrict__ t32,
                                             unsigned short* __restrict__ t16) {
  int i = blockIdx.x * 256 + threadIdx.x;   // 0 .. 5*4096
  if (i >= 5 * SP) return;
  int j = i >> 12, wh = i & (SP - 1);
  if (j < 4) {
    unsigned lo = (unsigned)tap_off(2 * j, wh);
    unsigned hi = (unsigned)tap_off(2 * j + 1, wh);
    t32[(j << 12) + wh] = lo | (hi << 16);
  } else {
    t16[wh] = (unsigned short)tap_off(8, wh);
  }
}

// y[b,o,n] = sum_c attn_w[o][c]*x[b,c,n] -> d_out.  LDS-free.
// Grid (x = B*16 slabs fastest -> slab%8 pins all 8 o-tiles of a slab to one
// XCD L2; y = 8 o-tiles). Block 256 thr = 4 waves; thread = 4o x 4n.
// Per 4-c chunk: 4 wave-uniform float4 w loads (L1 broadcast) + 4 coalesced
// 1KB float4 x loads + 64 FMA.
__global__ __launch_bounds__(256) void k_conv(
    const float* __restrict__ x, const float* __restrict__ w,
    float* __restrict__ y) {
  int slab = blockIdx.x;               // b*16 + nslab
  int ot   = blockIdx.y;               // 0..7
  int b    = slab >> 4, ns = slab & 15;
  int lane = threadIdx.x & 63;
  int o0   = (ot << 4) + ((threadIdx.x >> 6) << 2);
  int n0   = (ns << 8) + (lane << 2);

  const float* xb = x + ((size_t)b << 19) + n0;

  float acc[4][4];
#pragma unroll
  for (int i = 0; i < 4; i++)
#pragma unroll
    for (int j = 0; j < 4; j++) acc[i][j] = 0.0f;

#pragma unroll 2
  for (int c0 = 0; c0 < CCH; c0 += 4) {
    float4 xv[4], wv[4];
#pragma unroll
    for (int i = 0; i < 4; i++)
      xv[i] = *(const float4*)&xb[(size_t)(c0 + i) << 12];   // coalesced
#pragma unroll
    for (int i = 0; i < 4; i++)
      wv[i] = *(const float4*)&w[((o0 + i) << 7) + c0];      // broadcast
#pragma unroll
    for (int i = 0; i < 4; i++) {
      float ws[4] = {wv[i].x, wv[i].y, wv[i].z, wv[i].w};
#pragma unroll
      for (int l = 0; l < 4; l++) {
        acc[i][0] = fmaf(ws[l], ((const float*)&xv[l])[0], acc[i][0]);
        acc[i][1] = fmaf(ws[l], ((const float*)&xv[l])[1], acc[i][1]);
        acc[i][2] = fmaf(ws[l], ((const float*)&xv[l])[2], acc[i][2]);
        acc[i][3] = fmaf(ws[l], ((const float*)&xv[l])[3], acc[i][3]);
      }
    }
  }

  float* yb = y + ((size_t)b << 19) + n0;
#pragma unroll
  for (int i = 0; i < 4; i++)
    *(float4*)&yb[(size_t)(o0 + i) << 12] =
        make_float4(acc[i][0], acc[i][1], acc[i][2], acc[i][3]);
}

// out[b,c,wh] = max_s G_s[src(s,wh)], G_s[p] = se[s]*x[p]*sigmoid(se[s]*y[p]+ab).
// Phase 1: G bands (1.4 sigmoids/output). Phase 2: 5 packed table loads +
// 9 ds_read_b32 + 9 fmax; OOB taps hit sentinel g[0] = 0 (no branches).
template <bool TBL>
__global__ __launch_bounds__(256) void k_attnmax(
    const float* __restrict__ x, float* __restrict__ yo,
    const float* __restrict__ se_param, const float* __restrict__ attn_b,
    const unsigned* __restrict__ t32, const unsigned short* __restrict__ t16) {
  __shared__ float g[GTOT + 1];
  __shared__ float se9[16];

  int bc = blockIdx.x;            // b*128 + c
  int c  = bc & (CCH - 1);
  const float* xp = x  + ((size_t)bc << 12);
  float*       yp = yo + ((size_t)bc << 12);

  if (threadIdx.x < 9) se9[threadIdx.x] = sigmoidf_(se_param[threadIdx.x]);
  if (threadIdx.x == 0) g[0] = 0.0f;
  float ab = attn_b[c];
  __syncthreads();

  // Phase 1: f -> (s, rb, sh); global source row rg = wilo(s) - 1 + rb.
  for (int f = threadIdx.x; f < 9 * 64 * BROWS; f += 256) {
    int s   = f / (64 * BROWS);
    int rem = f - s * (64 * BROWS);
    int rb  = rem >> 6, sh = rem & 63;
    int rg  = ((s * 64 * 58255) >> 19) - 1 + rb;   // wilo(s) = (s*64)/9
    float val = 0.0f;
    if ((unsigned)rg < 64u) {
      float se = se9[s];
      float xx = xp[(rg << 6) + sh];               // 256B coalesced rows
      float yy = yp[(rg << 6) + sh];
      float t  = __expf(-fmaf(se, yy, ab));
      val = se * xx * __builtin_amdgcn_rcpf(1.0f + t);
    }
    g[1 + s * BSZ + sh * BSTR + rb] = val;
  }
  __syncthreads();

  // Phase 2: gather + max; overwrite the y-plane with the result.
  for (int k = 0; k < 16; k++) {
    int wh = (k << 8) | threadIdx.x;
    float m;
    if (TBL) {
      unsigned p01 = t32[wh];
      unsigned p23 = t32[SP + wh];
      unsigned p45 = t32[2 * SP + wh];
      unsigned p67 = t32[3 * SP + wh];
      int p8 = t16[wh];
      float m0 = fmaxf(g[p01 & 0xffffu], g[p01 >> 16]);
      float m1 = fmaxf(g[p23 & 0xffffu], g[p23 >> 16]);
      float m2 = fmaxf(g[p45 & 0xffffu], g[p45 >> 16]);
      float m3 = fmaxf(g[p67 & 0xffffu], g[p67 >> 16]);
      m = fmaxf(fmaxf(fmaxf(m0, m1), fmaxf(m2, m3)), g[p8]);
    } else {
      m = -3.4e38f;
#pragma unroll
      for (int s = 0; s < 9; s++) m = fmaxf(m, g[tap_off(s, wh)]);
    }
    yp[wh] = m;
  }
}

extern "C" void kernel_launch(void* const* d_in, const int* in_sizes, int n_in,
                              void* d_out, int out_size, void* d_ws, size_t ws_size,
                              hipStream_t stream) {
  const float* x        = (const float*)d_in[0];
  const float* se_param = (const float*)d_in[1];
  const float* attn_w   = (const float*)d_in[2];
  const float* attn_b   = (const float*)d_in[3];
  float* out = (float*)d_out;

  int B = in_sizes[0] / (CCH * SP);
  unsigned* t32       = (unsigned*)d_ws;
  unsigned short* t16 = (unsigned short*)((char*)d_ws + T16_OFF);
  bool use_ws = ws_size >= (size_t)(T16_OFF + SP * sizeof(unsigned short));

  if (use_ws)
    k_tbl<<<dim3(80), dim3(256), 0, stream>>>(t32, t16);

  k_conv<<<dim3(B * 16, 8), dim3(256), 0, stream>>>(x, attn_w, out);

  if (use_ws)
    k_attnmax<true><<<dim3(B * CCH), dim3(256), 0, stream>>>(
        x, out, se_param, attn_b, t32, t16);
  else
    k_attnmax<false><<<dim3(B * CCH), dim3(256), 0, stream>>>(
        x, out, se_param, attn_b, nullptr, nullptr);
}

// Round 8
// 62.871 us; speedup vs baseline: 1.0159x; 1.0159x over previous
//
#include <hip/hip_runtime.h>

#define CCH 128
#define SP  4096          // 64*64 spatial positions per (b,c)
#define BSTR 11           // G-band stride per sh (floats); odd -> bank spread
#define BROWS 10          // band rows rb in [0,10)
#define BSZ (64 * BSTR)   // 704 floats per band
#define GTOT (9 * BSZ)    // 6336 floats; +1 sentinel slot at g[0]
#define T16_OFF 65536     // byte offset of the u16 (s=8) table in d_ws

__device__ __forceinline__ float sigmoidf_(float z) {
  return 1.0f / (1.0f + __expf(-z));
}

// Band-local gather offset for tap s at output wh: 1 + s*BSZ + sh*BSTR + rb,
// or 0 (sentinel -> g[0] = 0.0f) when the source pixel is out of bounds.
__device__ __forceinline__ int tap_off(int s, int wh) {
  int q  = (s << 12) + wh;     // flat index into torch's reinterpreted view
  int wi = q / 576;  int r  = q - wi * 576;
  int hi = r / 9;    int kk = r - hi * 9;
  int di = kk / 3,   dj = kk - di * 3;
  int sw = wi + di - 1, sh = hi + dj - 1;
  bool valid = ((unsigned)sw < 64u) & ((unsigned)sh < 64u);
  int wilo = (s * 64) / 9;     // first source row of band s
  return valid ? (1 + s * BSZ + sh * BSTR + (sw - wilo + 1)) : 0;
}

// One-time table: taps packed as 4 u32 pairs (s=0..7) + 1 u16 (s=8) per wh.
__global__ __launch_bounds__(256) void k_tbl(unsigned* __restrict__ t32,
                                             unsigned short* __restrict__ t16) {
  int i = blockIdx.x * 256 + threadIdx.x;   // 0 .. 5*4096
  if (i >= 5 * SP) return;
  int j = i >> 12, wh = i & (SP - 1);
  if (j < 4) {
    unsigned lo = (unsigned)tap_off(2 * j, wh);
    unsigned hi = (unsigned)tap_off(2 * j + 1, wh);
    t32[(j << 12) + wh] = lo | (hi << 16);
  } else {
    t16[wh] = (unsigned short)tap_off(8, wh);
  }
}

// y[b,o,n] = sum_c attn_w[o][c]*x[b,c,n] -> d_out.  LDS-free.
// Grid (x = B*16 slabs fastest -> slab%8 pins all 8 o-tiles of a slab to one
// XCD L2; y = 8 o-tiles). Block 256 thr = 4 waves; thread = 4o x 4n.
// Per 4-c chunk: 4 wave-uniform float4 w loads (L1 broadcast) + 4 coalesced
// 1KB float4 x loads + 64 FMA.
__global__ __launch_bounds__(256) void k_conv(
    const float* __restrict__ x, const float* __restrict__ w,
    float* __restrict__ y) {
  int slab = blockIdx.x;               // b*16 + nslab
  int ot   = blockIdx.y;               // 0..7
  int b    = slab >> 4, ns = slab & 15;
  int lane = threadIdx.x & 63;
  int o0   = (ot << 4) + ((threadIdx.x >> 6) << 2);
  int n0   = (ns << 8) + (lane << 2);

  const float* xb = x + ((size_t)b << 19) + n0;

  float acc[4][4];
#pragma unroll
  for (int i = 0; i < 4; i++)
#pragma unroll
    for (int j = 0; j < 4; j++) acc[i][j] = 0.0f;

#pragma unroll 2
  for (int c0 = 0; c0 < CCH; c0 += 4) {
    float4 xv[4], wv[4];
#pragma unroll
    for (int i = 0; i < 4; i++)
      xv[i] = *(const float4*)&xb[(size_t)(c0 + i) << 12];   // coalesced
#pragma unroll
    for (int i = 0; i < 4; i++)
      wv[i] = *(const float4*)&w[((o0 + i) << 7) + c0];      // broadcast
#pragma unroll
    for (int i = 0; i < 4; i++) {
      float ws[4] = {wv[i].x, wv[i].y, wv[i].z, wv[i].w};
#pragma unroll
      for (int l = 0; l < 4; l++) {
        acc[i][0] = fmaf(ws[l], ((const float*)&xv[l])[0], acc[i][0]);
        acc[i][1] = fmaf(ws[l], ((const float*)&xv[l])[1], acc[i][1]);
        acc[i][2] = fmaf(ws[l], ((const float*)&xv[l])[2], acc[i][2]);
        acc[i][3] = fmaf(ws[l], ((const float*)&xv[l])[3], acc[i][3]);
      }
    }
  }

  float* yb = y + ((size_t)b << 19) + n0;
#pragma unroll
  for (int i = 0; i < 4; i++)
    *(float4*)&yb[(size_t)(o0 + i) << 12] =
        make_float4(acc[i][0], acc[i][1], acc[i][2], acc[i][3]);
}

// out[b,c,wh] = max_s G_s[src(s,wh)], G_s[p] = se[s]*x[p]*sigmoid(se[s]*y[p]+ab).
// Phase 1: G bands (1.4 sigmoids/output). Phase 2: 5 packed table loads +
// 9 ds_read_b32 + 9 fmax; OOB taps hit sentinel g[0] = 0 (no branches).
template <bool TBL>
__global__ __launch_bounds__(256) void k_attnmax(
    const float* __restrict__ x, float* __restrict__ yo,
    const float* __restrict__ se_param, const float* __restrict__ attn_b,
    const unsigned* __restrict__ t32, const unsigned short* __restrict__ t16) {
  __shared__ float g[GTOT + 1];
  __shared__ float se9[16];

  int bc = blockIdx.x;            // b*128 + c
  int c  = bc & (CCH - 1);
  const float* xp = x  + ((size_t)bc << 12);
  float*       yp = yo + ((size_t)bc << 12);

  if (threadIdx.x < 9) se9[threadIdx.x] = sigmoidf_(se_param[threadIdx.x]);
  if (threadIdx.x == 0) g[0] = 0.0f;
  float ab = attn_b[c];
  __syncthreads();

  // Phase 1: f -> (s, rb, sh); global source row rg = wilo(s) - 1 + rb.
  for (int f = threadIdx.x; f < 9 * 64 * BROWS; f += 256) {
    int s   = f / (64 * BROWS);
    int rem = f - s * (64 * BROWS);
    int rb  = rem >> 6, sh = rem & 63;
    int rg  = ((s * 64 * 58255) >> 19) - 1 + rb;   // wilo(s) = (s*64)/9
    float val = 0.0f;
    if ((unsigned)rg < 64u) {
      float se = se9[s];
      float xx = xp[(rg << 6) + sh];               // 256B coalesced rows
      float yy = yp[(rg << 6) + sh];
      float t  = __expf(-fmaf(se, yy, ab));
      val = se * xx * __builtin_amdgcn_rcpf(1.0f + t);
    }
    g[1 + s * BSZ + sh * BSTR + rb] = val;
  }
  __syncthreads();

  // Phase 2: gather + max; overwrite the y-plane with the result.
  for (int k = 0; k < 16; k++) {
    int wh = (k << 8) | threadIdx.x;
    float m;
    if (TBL) {
      unsigned p01 = t32[wh];
      unsigned p23 = t32[SP + wh];
      unsigned p45 = t32[2 * SP + wh];
      unsigned p67 = t32[3 * SP + wh];
      int p8 = t16[wh];
      float m0 = fmaxf(g[p01 & 0xffffu], g[p01 >> 16]);
      float m1 = fmaxf(g[p23 & 0xffffu], g[p23 >> 16]);
      float m2 = fmaxf(g[p45 & 0xffffu], g[p45 >> 16]);
      float m3 = fmaxf(g[p67 & 0xffffu], g[p67 >> 16]);
      m = fmaxf(fmaxf(fmaxf(m0, m1), fmaxf(m2, m3)), g[p8]);
    } else {
      m = -3.4e38f;
#pragma unroll
      for (int s = 0; s < 9; s++) m = fmaxf(m, g[tap_off(s, wh)]);
    }
    yp[wh] = m;
  }
}

extern "C" void kernel_launch(void* const* d_in, const int* in_sizes, int n_in,
                              void* d_out, int out_size, void* d_ws, size_t ws_size,
                              hipStream_t stream) {
  const float* x        = (const float*)d_in[0];
  const float* se_param = (const float*)d_in[1];
  const float* attn_w   = (const float*)d_in[2];
  const float* attn_b   = (const float*)d_in[3];
  float* out = (float*)d_out;

  int B = in_sizes[0] / (CCH * SP);
  unsigned* t32       = (unsigned*)d_ws;
  unsigned short* t16 = (unsigned short*)((char*)d_ws + T16_OFF);
  bool use_ws = ws_size >= (size_t)(T16_OFF + SP * sizeof(unsigned short));

  if (use_ws)
    k_tbl<<<dim3(80), dim3(256), 0, stream>>>(t32, t16);

  k_conv<<<dim3(B * 16, 8), dim3(256), 0, stream>>>(x, attn_w, out);

  if (use_ws)
    k_attnmax<true><<<dim3(B * CCH), dim3(256), 0, stream>>>(
        x, out, se_param, attn_b, t32, t16);
  else
    k_attnmax<false><<<dim3(B * CCH), dim3(256), 0, stream>>>(
        x, out, se_param, attn_b, nullptr, nullptr);
}

// Round 9
// 62.772 us; speedup vs baseline: 1.0175x; 1.0016x over previous
//
#include <hip/hip_runtime.h>

#define CCH 128
#define SP  4096          // 64*64 spatial positions per (b,c)
#define BSTR 11           // G-band stride per sh (floats); odd -> bank spread
#define BROWS 10          // band rows rb in [0,10)
#define BSZ (64 * BSTR)   // 704 floats per band
#define GTOT (9 * BSZ)    // 6336 floats; +1 sentinel slot at g[0]
#define T16_OFF 65536     // byte offset of the u16 (s=8) table in d_ws

__device__ __forceinline__ float sigmoidf_(float z) {
  return 1.0f / (1.0f + __expf(-z));
}

// Band-local gather offset for tap s at output wh: 1 + s*BSZ + sh*BSTR + rb,
// or 0 (sentinel -> g[0] = 0.0f) when the source pixel is out of bounds.
__device__ __forceinline__ int tap_off(int s, int wh) {
  int q  = (s << 12) + wh;     // flat index into torch's reinterpreted view
  int wi = q / 576;  int r  = q - wi * 576;
  int hi = r / 9;    int kk = r - hi * 9;
  int di = kk / 3,   dj = kk - di * 3;
  int sw = wi + di - 1, sh = hi + dj - 1;
  bool valid = ((unsigned)sw < 64u) & ((unsigned)sh < 64u);
  int wilo = (s * 64) / 9;     // first source row of band s
  return valid ? (1 + s * BSZ + sh * BSTR + (sw - wilo + 1)) : 0;
}

// One-time table: taps packed as 4 u32 pairs (s=0..7) + 1 u16 (s=8) per wh.
__global__ __launch_bounds__(256) void k_tbl(unsigned* __restrict__ t32,
                                             unsigned short* __restrict__ t16) {
  int i = blockIdx.x * 256 + threadIdx.x;   // 0 .. 5*4096
  if (i >= 5 * SP) return;
  int j = i >> 12, wh = i & (SP - 1);
  if (j < 4) {
    unsigned lo = (unsigned)tap_off(2 * j, wh);
    unsigned hi = (unsigned)tap_off(2 * j + 1, wh);
    t32[(j << 12) + wh] = lo | (hi << 16);
  } else {
    t16[wh] = (unsigned short)tap_off(8, wh);
  }
}

// y[b,o,n] = sum_c attn_w[o][c]*x[b,c,n] -> d_out.  LDS-free.
// Grid (x = B*16 slabs fastest -> slab%8 pins all 8 o-tiles of a slab to one
// XCD L2; y = 8 o-tiles). Block 256 thr = 4 waves; thread = 4o x 4n.
// Per 4-c chunk: 4 wave-uniform float4 w loads (L1 broadcast) + 4 coalesced
// 1KB float4 x loads + 64 FMA.
__global__ __launch_bounds__(256) void k_conv(
    const float* __restrict__ x, const float* __restrict__ w,
    float* __restrict__ y) {
  int slab = blockIdx.x;               // b*16 + nslab
  int ot   = blockIdx.y;               // 0..7
  int b    = slab >> 4, ns = slab & 15;
  int lane = threadIdx.x & 63;
  int o0   = (ot << 4) + ((threadIdx.x >> 6) << 2);
  int n0   = (ns << 8) + (lane << 2);

  const float* xb = x + ((size_t)b << 19) + n0;

  float acc[4][4];
#pragma unroll
  for (int i = 0; i < 4; i++)
#pragma unroll
    for (int j = 0; j < 4; j++) acc[i][j] = 0.0f;

#pragma unroll 2
  for (int c0 = 0; c0 < CCH; c0 += 4) {
    float4 xv[4], wv[4];
#pragma unroll
    for (int i = 0; i < 4; i++)
      xv[i] = *(const float4*)&xb[(size_t)(c0 + i) << 12];   // coalesced
#pragma unroll
    for (int i = 0; i < 4; i++)
      wv[i] = *(const float4*)&w[((o0 + i) << 7) + c0];      // broadcast
#pragma unroll
    for (int i = 0; i < 4; i++) {
      float ws[4] = {wv[i].x, wv[i].y, wv[i].z, wv[i].w};
#pragma unroll
      for (int l = 0; l < 4; l++) {
        acc[i][0] = fmaf(ws[l], ((const float*)&xv[l])[0], acc[i][0]);
        acc[i][1] = fmaf(ws[l], ((const float*)&xv[l])[1], acc[i][1]);
        acc[i][2] = fmaf(ws[l], ((const float*)&xv[l])[2], acc[i][2]);
        acc[i][3] = fmaf(ws[l], ((const float*)&xv[l])[3], acc[i][3]);
      }
    }
  }

  float* yb = y + ((size_t)b << 19) + n0;
#pragma unroll
  for (int i = 0; i < 4; i++)
    *(float4*)&yb[(size_t)(o0 + i) << 12] =
        make_float4(acc[i][0], acc[i][1], acc[i][2], acc[i][3]);
}

// out[b,c,wh] = max_s G_s[src(s,wh)], G_s[p] = se[s]*x[p]*sigmoid(se[s]*y[p]+ab).
// Phase 1: G bands (1.4 sigmoids/output). Phase 2: 5 packed table loads +
// 9 ds_read_b32 + 9 fmax; OOB taps hit sentinel g[0] = 0 (no branches).
template <bool TBL>
__global__ __launch_bounds__(256) void k_attnmax(
    const float* __restrict__ x, float* __restrict__ yo,
    const float* __restrict__ se_param, const float* __restrict__ attn_b,
    const unsigned* __restrict__ t32, const unsigned short* __restrict__ t16) {
  __shared__ float g[GTOT + 1];
  __shared__ float se9[16];

  int bc = blockIdx.x;            // b*128 + c
  int c  = bc & (CCH - 1);
  const float* xp = x  + ((size_t)bc << 12);
  float*       yp = yo + ((size_t)bc << 12);

  if (threadIdx.x < 9) se9[threadIdx.x] = sigmoidf_(se_param[threadIdx.x]);
  if (threadIdx.x == 0) g[0] = 0.0f;
  float ab = attn_b[c];
  __syncthreads();

  // Phase 1: f -> (s, rb, sh); global source row rg = wilo(s) - 1 + rb.
  for (int f = threadIdx.x; f < 9 * 64 * BROWS; f += 256) {
    int s   = f / (64 * BROWS);
    int rem = f - s * (64 * BROWS);
    int rb  = rem >> 6, sh = rem & 63;
    int rg  = ((s * 64 * 58255) >> 19) - 1 + rb;   // wilo(s) = (s*64)/9
    float val = 0.0f;
    if ((unsigned)rg < 64u) {
      float se = se9[s];
      float xx = xp[(rg << 6) + sh];               // 256B coalesced rows
      float yy = yp[(rg << 6) + sh];
      float t  = __expf(-fmaf(se, yy, ab));
      val = se * xx * __builtin_amdgcn_rcpf(1.0f + t);
    }
    g[1 + s * BSZ + sh * BSTR + rb] = val;
  }
  __syncthreads();

  // Phase 2: gather + max; overwrite the y-plane with the result.
  for (int k = 0; k < 16; k++) {
    int wh = (k << 8) | threadIdx.x;
    float m;
    if (TBL) {
      unsigned p01 = t32[wh];
      unsigned p23 = t32[SP + wh];
      unsigned p45 = t32[2 * SP + wh];
      unsigned p67 = t32[3 * SP + wh];
      int p8 = t16[wh];
      float m0 = fmaxf(g[p01 & 0xffffu], g[p01 >> 16]);
      float m1 = fmaxf(g[p23 & 0xffffu], g[p23 >> 16]);
      float m2 = fmaxf(g[p45 & 0xffffu], g[p45 >> 16]);
      float m3 = fmaxf(g[p67 & 0xffffu], g[p67 >> 16]);
      m = fmaxf(fmaxf(fmaxf(m0, m1), fmaxf(m2, m3)), g[p8]);
    } else {
      m = -3.4e38f;
#pragma unroll
      for (int s = 0; s < 9; s++) m = fmaxf(m, g[tap_off(s, wh)]);
    }
    yp[wh] = m;
  }
}

extern "C" void kernel_launch(void* const* d_in, const int* in_sizes, int n_in,
                              void* d_out, int out_size, void* d_ws, size_t ws_size,
                              hipStream_t stream) {
  const float* x        = (const float*)d_in[0];
  const float* se_param = (const float*)d_in[1];
  const float* attn_w   = (const float*)d_in[2];
  const float* attn_b   = (const float*)d_in[3];
  float* out = (float*)d_out;

  int B = in_sizes[0] / (CCH * SP);
  unsigned* t32       = (unsigned*)d_ws;
  unsigned short* t16 = (unsigned short*)((char*)d_ws + T16_OFF);
  bool use_ws = ws_size >= (size_t)(T16_OFF + SP * sizeof(unsigned short));

  if (use_ws)
    k_tbl<<<dim3(80), dim3(256), 0, stream>>>(t32, t16);

  k_conv<<<dim3(B * 16, 8), dim3(256), 0, stream>>>(x, attn_w, out);

  if (use_ws)
    k_attnmax<true><<<dim3(B * CCH), dim3(256), 0, stream>>>(
        x, out, se_param, attn_b, t32, t16);
  else
    k_attnmax<false><<<dim3(B * CCH), dim3(256), 0, stream>>>(
        x, out, se_param, attn_b, nullptr, nullptr);
}